// Round 9
// baseline (205.282 us; speedup 1.0000x reference)
//
#include <hip/hip_runtime.h>
#include <hip/hip_bf16.h>

#define NEG_SLOPE 0.2f
#define EPB 4096   // edges per block in bucket_scatter (256 thr x 16)
#define NHB 64     // hist blocks

typedef __attribute__((ext_vector_type(8))) short short8v;   // 8 bf16 bit-patterns
typedef __attribute__((ext_vector_type(4))) float f32x4;

__device__ inline float blo(unsigned u) { return __uint_as_float(u << 16); }
__device__ inline float bhi(unsigned u) { return __uint_as_float(u & 0xffff0000u); }
__device__ inline unsigned short bf16bits(float f) {
    __hip_bfloat16 b = __float2bfloat16(f);
    return *(unsigned short*)&b;
}
__device__ inline unsigned pack2bf(float e, float o) {
    return ((unsigned)bf16bits(o) << 16) | (unsigned)bf16bits(e);
}

// ---------------------------------------------------------------------------
// Shared NT pieces (augmented W^T in LDS; 64x80 MFMA tile).
// ---------------------------------------------------------------------------
template <int K>
__device__ inline void stage_sBt(unsigned short* sBt,
                                 const float* __restrict__ W_src,
                                 const float* __restrict__ a_src,
                                 const float* __restrict__ W_dst,
                                 const float* __restrict__ a_dst, int tid) {
    constexpr int PAD = K + 8;
    for (int i = tid; i < 64 * K; i += 256) {
        int k = i >> 6, j = i & 63;
        sBt[j * PAD + k] = bf16bits(W_src[i]);
    }
    for (int i = tid; i < 2 * K; i += 256) {
        int which = (i >= K) ? 1 : 0;
        int k = i - which * K;
        const float* Wr = (which ? W_dst : W_src) + k * 64;
        const float* av = which ? a_dst : a_src;
        float s = 0.f;
        #pragma unroll
        for (int j = 0; j < 64; ++j) s += Wr[j] * av[j];
        sBt[(64 + which) * PAD + k] = bf16bits(s);
    }
    for (int i = tid; i < 14 * K; i += 256) {
        int j = 66 + i / K, k = i % K;
        sBt[j * PAD + k] = 0;
    }
}

template <int K>
__device__ inline void nt_mfma_body(const unsigned short* sBt,
                                    const unsigned short* sX,
                                    int rowblockbase,
                                    unsigned* __restrict__ hb_out,
                                    float* __restrict__ alpha_src,
                                    float* __restrict__ alpha_dst,
                                    int N, int tid) {
    constexpr int PAD = K + 8;
    int wid = tid >> 6, l = tid & 63;
    int jcol = l & 15;

    f32x4 acc[5];
    #pragma unroll
    for (int t = 0; t < 5; ++t) acc[t] = (f32x4){0.f, 0.f, 0.f, 0.f};

    const unsigned short* xrow = &sX[(wid * 16 + (l & 15)) * PAD + (l >> 4) * 8];
    #pragma unroll
    for (int kt = 0; kt < K / 32; ++kt) {
        short8v a = *(const short8v*)(xrow + kt * 32);
        int kbase = kt * 32 + (l >> 4) * 8;
        #pragma unroll
        for (int t = 0; t < 5; ++t) {
            short8v b = *(const short8v*)&sBt[(t * 16 + jcol) * PAD + kbase];
            acc[t] = __builtin_amdgcn_mfma_f32_16x16x32_bf16(a, b, acc[t], 0, 0, 0);
        }
    }

    int rbase = rowblockbase + wid * 16 + (l >> 4) * 4;
    #pragma unroll
    for (int t = 0; t < 4; ++t) {
        #pragma unroll
        for (int r = 0; r < 4; ++r) {
            float v = acc[t][r];
            float w = __shfl_xor(v, 1);
            int row = rbase + r;
            if (!(l & 1) && row < N)
                hb_out[(size_t)row * 32 + t * 8 + (jcol >> 1)] = pack2bf(v, w);
        }
    }
    #pragma unroll
    for (int r = 0; r < 4; ++r) {
        int row = rbase + r;
        if (row < N) {
            if (jcol == 0) alpha_src[row] = acc[4][r];
            if (jcol == 1) alpha_dst[row] = acc[4][r];
        }
    }
}

// ---------------------------------------------------------------------------
// Dispatch 1: NT layer-1 (blocks [0, ntb)) + histogram partials.
// ---------------------------------------------------------------------------
__global__ __launch_bounds__(256) void fused_nt1_hist(
    const float* __restrict__ x,
    const float* __restrict__ W_src, const float* __restrict__ a_src,
    const float* __restrict__ W_dst, const float* __restrict__ a_dst,
    unsigned* __restrict__ hb_out, float* __restrict__ alpha_src,
    float* __restrict__ alpha_dst, int N,
    const int* __restrict__ dst, int* __restrict__ partials, int E, int ntb) {
    constexpr int K = 128, PAD = K + 8;
    __shared__ unsigned short sBt[80 * PAD];
    __shared__ unsigned short sX[64 * PAD];
    __shared__ int lh[256];
    int tid = threadIdx.x;

    if ((int)blockIdx.x >= ntb) {
        int bh = blockIdx.x - ntb;
        lh[tid] = 0;
        __syncthreads();
        for (int e = bh * 256 + tid; e < E; e += NHB * 256)
            atomicAdd(&lh[dst[e] >> 8], 1);
        __syncthreads();
        partials[bh * 256 + tid] = lh[tid];
        return;
    }

    stage_sBt<K>(sBt, W_src, a_src, W_dst, a_dst, tid);
    for (int idx = tid; idx < 64 * K / 4; idx += 256) {
        int row = (idx * 4) / K, col = (idx * 4) % K;
        int g = blockIdx.x * 64 + row;
        const float4 f = *(const float4*)(x + (size_t)((g < N) ? g : N - 1) * K + col);
        unsigned short* d = &sX[row * PAD + col];
        d[0] = bf16bits(f.x); d[1] = bf16bits(f.y);
        d[2] = bf16bits(f.z); d[3] = bf16bits(f.w);
    }
    __syncthreads();
    nt_mfma_body<K>(sBt, sX, blockIdx.x * 64, hb_out, alpha_src, alpha_dst, N, tid);
}

// ---------------------------------------------------------------------------
// Standalone NT (layer 2, bf16 input).
// ---------------------------------------------------------------------------
template <int K>
__global__ __launch_bounds__(256) void nt_bf16(
    const unsigned short* __restrict__ x,   // [N][K] bf16
    const float* __restrict__ W_src, const float* __restrict__ a_src,
    const float* __restrict__ W_dst, const float* __restrict__ a_dst,
    unsigned* __restrict__ hb_out, float* __restrict__ alpha_src,
    float* __restrict__ alpha_dst, int N) {
    constexpr int PAD = K + 8;
    __shared__ unsigned short sBt[80 * PAD];
    __shared__ unsigned short sX[64 * PAD];
    int tid = threadIdx.x;
    stage_sBt<K>(sBt, W_src, a_src, W_dst, a_dst, tid);
    for (int idx = tid; idx < 64 * K / 8; idx += 256) {
        int row = (idx * 8) / K, col = (idx * 8) % K;
        int g = blockIdx.x * 64 + row;
        short8v v = *(const short8v*)(x + (size_t)((g < N) ? g : N - 1) * K + col);
        *(short8v*)&sX[row * PAD + col] = v;
    }
    __syncthreads();
    nt_mfma_body<K>(sBt, sX, blockIdx.x * 64, hb_out, alpha_src, alpha_dst, N, tid);
}

// ---------------------------------------------------------------------------
// Dispatches 2-4: CSR build (scan, scatter, per-bucket finalize).
// ---------------------------------------------------------------------------
__global__ __launch_bounds__(256) void bucket_scan(const int* __restrict__ partials,
                                                   int* __restrict__ bucket_base,
                                                   int* __restrict__ bucket_cursor) {
    __shared__ int tmp[256];
    int tid = threadIdx.x;
    int v = 0;
    #pragma unroll 8
    for (int b = 0; b < NHB; ++b) v += partials[b * 256 + tid];
    tmp[tid] = v;
    __syncthreads();
    for (int off = 1; off < 256; off <<= 1) {
        int t = (tid >= off) ? tmp[tid - off] : 0;
        __syncthreads();
        tmp[tid] += t;
        __syncthreads();
    }
    int excl = tmp[tid] - v;
    bucket_base[tid] = excl;
    bucket_cursor[tid] = excl;
    if (tid == 255) bucket_base[256] = tmp[255];
}

__global__ __launch_bounds__(256) void bucket_scatter(const int* __restrict__ src,
                                                      const int* __restrict__ dst,
                                                      int* __restrict__ bucket_cursor,
                                                      unsigned* __restrict__ ebuf, int E) {
    __shared__ int lhist[256];
    __shared__ int lbase[256];
    int tid = threadIdx.x;
    lhist[tid] = 0;
    __syncthreads();
    int base = blockIdx.x * EPB;
    int bkt[16], rank[16];
    unsigned pack[16];
    #pragma unroll
    for (int i = 0; i < 16; ++i) {
        int e = base + i * 256 + tid;
        bkt[i] = -1;
        if (e < E) {
            int d = dst[e], s = src[e];
            bkt[i]  = d >> 8;
            pack[i] = ((unsigned)(d & 255) << 16) | (unsigned)s;
            rank[i] = atomicAdd(&lhist[bkt[i]], 1);
        }
    }
    __syncthreads();
    int cnt = lhist[tid];
    if (cnt) lbase[tid] = atomicAdd(&bucket_cursor[tid], cnt);
    __syncthreads();
    #pragma unroll
    for (int i = 0; i < 16; ++i)
        if (bkt[i] >= 0) ebuf[lbase[bkt[i]] + rank[i]] = pack[i];
}

__global__ __launch_bounds__(256) void bucket_build(const unsigned* __restrict__ ebuf,
                                                    const int* __restrict__ bucket_base,
                                                    int* __restrict__ row_ptr,
                                                    int* __restrict__ csr_src,
                                                    int N, int E) {
    __shared__ int deg[256];
    __shared__ int cur[256];
    __shared__ int tmp[256];
    int b = blockIdx.x, tid = threadIdx.x;
    int ebase = bucket_base[b], eend = bucket_base[b + 1];
    deg[tid] = 0;
    __syncthreads();
    for (int e = ebase + tid; e < eend; e += 256)
        atomicAdd(&deg[ebuf[e] >> 16], 1);
    __syncthreads();
    int v = deg[tid];
    tmp[tid] = v;
    __syncthreads();
    for (int off = 1; off < 256; off <<= 1) {
        int t = (tid >= off) ? tmp[tid - off] : 0;
        __syncthreads();
        tmp[tid] += t;
        __syncthreads();
    }
    int excl = tmp[tid] - v;
    int node = b * 256 + tid;
    if (node < N) row_ptr[node] = ebase + excl;
    if (b == 0 && tid == 0) row_ptr[N] = E;
    cur[tid] = excl;
    __syncthreads();
    for (int e = ebase + tid; e < eend; e += 256) {
        unsigned pk = ebuf[e];
        int r = atomicAdd(&cur[pk >> 16], 1);
        csr_src[ebase + r] = (int)(pk & 0xFFFFu);
    }
}

// ---------------------------------------------------------------------------
// agg_logits: wave per dst node; write NORMALIZED per-edge alpha (fp32, nt).
// Direct exp (logits O(10), fp32-safe; ratio == max-subtracted form).
// ---------------------------------------------------------------------------
__global__ __launch_bounds__(256) void agg_logits(
    const int* __restrict__ row_ptr, const int* __restrict__ csr_src,
    const float* __restrict__ alpha_src, const float* __restrict__ alpha_dst,
    float* __restrict__ palpha, int N) {
    int wid = threadIdx.x >> 6, lane = threadIdx.x & 63;
    int node = blockIdx.x * 4 + wid;
    if (node >= N) return;
    int beg = row_ptr[node], end = row_ptr[node + 1];
    float adst = alpha_dst[node];
    int deg = end - beg;

    if (deg <= 64) {
        float p = 0.f;
        if (lane < deg) {
            int s = __builtin_nontemporal_load(&csr_src[beg + lane]);
            float t = alpha_src[s] + adst;
            t = (t > 0.f) ? t : NEG_SLOPE * t;
            p = __expf(fminf(t, 60.f));
        }
        float denom = p;
        #pragma unroll
        for (int off = 32; off; off >>= 1) denom += __shfl_xor(denom, off);
        float inv = (denom > 0.f) ? 1.f / denom : 0.f;
        if (lane < deg)
            __builtin_nontemporal_store(p * inv, &palpha[beg + lane]);
    } else {
        float dL = 0.f;
        for (int c = beg; c < end; c += 64) {
            int e = c + lane;
            if (e < end) {
                int s = __builtin_nontemporal_load(&csr_src[e]);
                float t = alpha_src[s] + adst;
                t = (t > 0.f) ? t : NEG_SLOPE * t;
                float p = __expf(fminf(t, 60.f));
                palpha[e] = p;
                dL += p;
            }
        }
        float denom = dL;
        #pragma unroll
        for (int off = 32; off; off >>= 1) denom += __shfl_xor(denom, off);
        float inv = (denom > 0.f) ? 1.f / denom : 0.f;
        for (int c = beg; c < end; c += 64) {
            int e = c + lane;
            if (e < end) palpha[e] *= inv;
        }
    }
}

// ---------------------------------------------------------------------------
// agg_gather<HALF,OUTBF16>: wave per dst node; gather only a 64B half-row
// per edge (half-array = 3.2 MB -> per-XCD-L2 resident). 16-lane group per
// edge (lane = u32 = 2 bf16 feats); 32 edges per inner step = 8 loads in
// flight. Streams (csr, palpha, out) are non-temporal so they don't evict h.
// ---------------------------------------------------------------------------
template <int HALF, bool OUTBF16>
__global__ __launch_bounds__(256) void agg_gather(
    const int* __restrict__ row_ptr, const int* __restrict__ csr_src,
    const float* __restrict__ palpha,
    const unsigned* __restrict__ hb,    // [N][32] packed bf16x2
    const float* __restrict__ bias,     // [64]
    void* __restrict__ out_, int N) {
    int wid = threadIdx.x >> 6, lane = threadIdx.x & 63;
    int node = blockIdx.x * 4 + wid;
    if (node >= N) return;
    int beg = row_ptr[node], end = row_ptr[node + 1];
    int grp = lane >> 4, sub = lane & 15;
    const unsigned* hbh = hb + HALF * 16;

    float aA[4] = {0.f, 0.f, 0.f, 0.f};
    float aB[4] = {0.f, 0.f, 0.f, 0.f};

    for (int c = beg; c < end; c += 64) {
        int cnt = end - c;
        cnt = (cnt < 64) ? cnt : 64;
        int s = 0;
        float a = 0.f;
        if (lane < cnt) {
            s = __builtin_nontemporal_load(&csr_src[c + lane]);
            a = __builtin_nontemporal_load(&palpha[c + lane]);
        }
        for (int j = 0; j < cnt; j += 32) {
            int sv[8];
            float av[8];
            unsigned uv[8];
            #pragma unroll
            for (int i = 0; i < 8; ++i) {
                int e = j + 4 * i + grp;
                sv[i] = __shfl(s, e);
                av[i] = __shfl(a, e);
            }
            #pragma unroll
            for (int i = 0; i < 8; ++i)
                uv[i] = hbh[(size_t)sv[i] * 32 + sub];
            #pragma unroll
            for (int i = 0; i < 8; ++i) {
                aA[i & 3] = fmaf(av[i], blo(uv[i]), aA[i & 3]);
                aB[i & 3] = fmaf(av[i], bhi(uv[i]), aB[i & 3]);
            }
        }
    }
    float A = (aA[0] + aA[1]) + (aA[2] + aA[3]);
    float B = (aB[0] + aB[1]) + (aB[2] + aB[3]);
    A += __shfl_xor(A, 16); A += __shfl_xor(A, 32);
    B += __shfl_xor(B, 16); B += __shfl_xor(B, 32);

    int f0 = HALF * 32 + 2 * sub;
    float v0 = tanhf(A + bias[f0]);
    float v1 = tanhf(B + bias[f0 + 1]);

    if (grp == 0) {
        if constexpr (OUTBF16) {
            __builtin_nontemporal_store(pack2bf(v0, v1),
                (unsigned*)out_ + (size_t)node * 32 + HALF * 16 + sub);
        } else {
            float* op = (float*)out_ + (size_t)node * 64 + f0;
            __builtin_nontemporal_store(v0, op);
            __builtin_nontemporal_store(v1, op + 1);
        }
    }
}

// ---------------------------------------------------------------------------
extern "C" void kernel_launch(void* const* d_in, const int* in_sizes, int n_in,
                              void* d_out, int out_size, void* d_ws, size_t ws_size,
                              hipStream_t stream) {
    const float* x      = (const float*)d_in[0];
    const int*   src    = (const int*)  d_in[1];
    const int*   dst    = (const int*)  d_in[2];
    const float* W1_src = (const float*)d_in[3];
    const float* W1_dst = (const float*)d_in[4];
    const float* a1_src = (const float*)d_in[5];
    const float* a1_dst = (const float*)d_in[6];
    const float* b1     = (const float*)d_in[7];
    const float* W2_src = (const float*)d_in[8];
    const float* W2_dst = (const float*)d_in[9];
    const float* a2_src = (const float*)d_in[10];
    const float* a2_dst = (const float*)d_in[11];
    const float* b2     = (const float*)d_in[12];
    float* out = (float*)d_out;

    const int N = in_sizes[0] / 128;
    const int E = in_sizes[1];
    const int NB = (N + 255) / 256;

    char* ws = (char*)d_ws;
    size_t off = 0;
    auto alloc = [&](size_t bytes) {
        void* p = ws + off;
        off += (bytes + 255) & ~(size_t)255;
        return p;
    };
    unsigned* hbuf1  = (unsigned*)alloc((size_t)N * 32 * 4);  // h layer-1 (bf16x2)
    unsigned* h1buf  = (unsigned*)alloc((size_t)N * 32 * 4);  // tanh'd agg1 out (bf16x2)
    unsigned* hbuf2  = (unsigned*)alloc((size_t)N * 32 * 4);  // h layer-2 (bf16x2)
    float* alpha_s1  = (float*)alloc((size_t)N * 4);
    float* alpha_d1  = (float*)alloc((size_t)N * 4);
    float* alpha_s2  = (float*)alloc((size_t)N * 4);
    float* alpha_d2  = (float*)alloc((size_t)N * 4);
    float* palpha    = (float*)alloc((size_t)E * 4);
    int*   row_ptr   = (int*)  alloc((size_t)(N + 1) * 4);
    int*   csr_src   = (int*)  alloc((size_t)E * 4);
    int*   partials  = (int*)  alloc(NHB * 256 * 4);
    int*   bucket_base   = (int*)alloc(257 * 4);
    int*   bucket_cursor = (int*)alloc(256 * 4);
    unsigned* ebuf   = (unsigned*)alloc((size_t)E * 4);
    (void)ws_size;

    const int eb3  = (E + EPB - 1) / EPB;
    const int nwb  = (N + 3) / 4;            // wave-per-node kernels
    const int ntb  = (N + 63) / 64;          // NT tiles

    // CSR build chain (hist fused with NT1)
    fused_nt1_hist<<<ntb + NHB, 256, 0, stream>>>(
        x, W1_src, a1_src, W1_dst, a1_dst, hbuf1, alpha_s1, alpha_d1, N,
        dst, partials, E, ntb);
    bucket_scan<<<1, 256, 0, stream>>>(partials, bucket_base, bucket_cursor);
    bucket_scatter<<<eb3, 256, 0, stream>>>(src, dst, bucket_cursor, ebuf, E);
    bucket_build<<<NB, 256, 0, stream>>>(ebuf, bucket_base, row_ptr, csr_src, N, E);

    // Layer 1: logits -> two L2-resident half-gathers -> h1 (bf16)
    agg_logits<<<nwb, 256, 0, stream>>>(row_ptr, csr_src, alpha_s1, alpha_d1,
                                        palpha, N);
    agg_gather<0, true><<<nwb, 256, 0, stream>>>(row_ptr, csr_src, palpha,
                                                 hbuf1, b1, h1buf, N);
    agg_gather<1, true><<<nwb, 256, 0, stream>>>(row_ptr, csr_src, palpha,
                                                 hbuf1, b1, h1buf, N);

    // Layer 2
    nt_bf16<64><<<ntb, 256, 0, stream>>>((const unsigned short*)h1buf,
                                         W2_src, a2_src, W2_dst, a2_dst,
                                         hbuf2, alpha_s2, alpha_d2, N);
    agg_logits<<<nwb, 256, 0, stream>>>(row_ptr, csr_src, alpha_s2, alpha_d2,
                                        palpha, N);
    agg_gather<0, false><<<nwb, 256, 0, stream>>>(row_ptr, csr_src, palpha,
                                                  hbuf2, b2, out, N);
    agg_gather<1, false><<<nwb, 256, 0, stream>>>(row_ptr, csr_src, palpha,
                                                  hbuf2, b2, out, N);
}

// Round 10
// 144.363 us; speedup vs baseline: 1.4220x; 1.4220x over previous
//
#include <hip/hip_runtime.h>
#include <hip/hip_bf16.h>

#define NEG_SLOPE 0.2f
#define EPB 4096   // edges per block in bucket_scatter (256 thr x 16)
#define NHB 64     // hist blocks

typedef __attribute__((ext_vector_type(8))) short short8v;   // 8 bf16 bit-patterns
typedef __attribute__((ext_vector_type(4))) float f32x4;

__device__ inline float blo(unsigned u) { return __uint_as_float(u << 16); }
__device__ inline float bhi(unsigned u) { return __uint_as_float(u & 0xffff0000u); }
__device__ inline unsigned short bf16bits(float f) {
    __hip_bfloat16 b = __float2bfloat16(f);
    return *(unsigned short*)&b;
}
__device__ inline unsigned pack2bf(float e, float o) {
    return ((unsigned)bf16bits(o) << 16) | (unsigned)bf16bits(e);
}

// ---------------------------------------------------------------------------
// Prep: blocks [0,NHB) = histogram partials; block NHB = Wt1; block NHB+1 = Wt2.
// Wt[j][k] (bf16, [80][K]): j<64 -> W_src[k][j]; j=64 -> dot(W_src[k,:],a_src);
// j=65 -> dot(W_dst[k,:],a_dst); j in 66..79 -> 0.
// ---------------------------------------------------------------------------
template <int K>
__device__ inline void build_wt(unsigned short* __restrict__ Wt,
                                const float* __restrict__ W_src,
                                const float* __restrict__ a_src,
                                const float* __restrict__ W_dst,
                                const float* __restrict__ a_dst, int tid) {
    for (int i = tid; i < 64 * K; i += 256) {
        int k = i >> 6, j = i & 63;               // coalesced read of W_src
        Wt[j * K + k] = bf16bits(W_src[i]);
    }
    for (int i = tid; i < 2 * K; i += 256) {
        int which = (i >= K) ? 1 : 0;
        int k = i - which * K;
        const float* Wr = (which ? W_dst : W_src) + k * 64;
        const float* av = which ? a_dst : a_src;
        float s = 0.f;
        #pragma unroll
        for (int j = 0; j < 64; ++j) s += Wr[j] * av[j];
        Wt[(64 + which) * K + k] = bf16bits(s);
    }
    for (int i = tid; i < 14 * K; i += 256) Wt[66 * K + i] = 0;
}

__global__ __launch_bounds__(256) void prep(
    const int* __restrict__ dst, int* __restrict__ partials, int E,
    const float* __restrict__ W1_src, const float* __restrict__ a1_src,
    const float* __restrict__ W1_dst, const float* __restrict__ a1_dst,
    const float* __restrict__ W2_src, const float* __restrict__ a2_src,
    const float* __restrict__ W2_dst, const float* __restrict__ a2_dst,
    unsigned short* __restrict__ Wt1, unsigned short* __restrict__ Wt2) {
    __shared__ int lh[256];
    int tid = threadIdx.x, b = blockIdx.x;
    if (b < NHB) {
        lh[tid] = 0;
        __syncthreads();
        for (int e = b * 256 + tid; e < E; e += NHB * 256)
            atomicAdd(&lh[dst[e] >> 8], 1);
        __syncthreads();
        partials[b * 256 + tid] = lh[tid];
    } else if (b == NHB) {
        build_wt<128>(Wt1, W1_src, a1_src, W1_dst, a1_dst, tid);
    } else {
        build_wt<64>(Wt2, W2_src, a2_src, W2_dst, a2_dst, tid);
    }
}

// ---------------------------------------------------------------------------
// CSR build: scan, scatter, per-bucket finalize. bucket(node) = node >> 8.
// ---------------------------------------------------------------------------
__global__ __launch_bounds__(256) void bucket_scan(const int* __restrict__ partials,
                                                   int* __restrict__ bucket_base,
                                                   int* __restrict__ bucket_cursor) {
    __shared__ int tmp[256];
    int tid = threadIdx.x;
    int v = 0;
    #pragma unroll 8
    for (int b = 0; b < NHB; ++b) v += partials[b * 256 + tid];
    tmp[tid] = v;
    __syncthreads();
    for (int off = 1; off < 256; off <<= 1) {
        int t = (tid >= off) ? tmp[tid - off] : 0;
        __syncthreads();
        tmp[tid] += t;
        __syncthreads();
    }
    int excl = tmp[tid] - v;
    bucket_base[tid] = excl;
    bucket_cursor[tid] = excl;
    if (tid == 255) bucket_base[256] = tmp[255];
}

// ebuf entry = (dst&255)<<16 | src   (requires N <= 65536)
__global__ __launch_bounds__(256) void bucket_scatter(const int* __restrict__ src,
                                                      const int* __restrict__ dst,
                                                      int* __restrict__ bucket_cursor,
                                                      unsigned* __restrict__ ebuf, int E) {
    __shared__ int lhist[256];
    __shared__ int lbase[256];
    int tid = threadIdx.x;
    lhist[tid] = 0;
    __syncthreads();
    int base = blockIdx.x * EPB;
    int bkt[16], rank[16];
    unsigned pack[16];
    #pragma unroll
    for (int i = 0; i < 16; ++i) {
        int e = base + i * 256 + tid;
        bkt[i] = -1;
        if (e < E) {
            int d = dst[e], s = src[e];
            bkt[i]  = d >> 8;
            pack[i] = ((unsigned)(d & 255) << 16) | (unsigned)s;
            rank[i] = atomicAdd(&lhist[bkt[i]], 1);
        }
    }
    __syncthreads();
    int cnt = lhist[tid];
    if (cnt) lbase[tid] = atomicAdd(&bucket_cursor[tid], cnt);
    __syncthreads();
    #pragma unroll
    for (int i = 0; i < 16; ++i)
        if (bkt[i] >= 0) ebuf[lbase[bkt[i]] + rank[i]] = pack[i];
}

__global__ __launch_bounds__(256) void bucket_build(const unsigned* __restrict__ ebuf,
                                                    const int* __restrict__ bucket_base,
                                                    int* __restrict__ row_ptr,
                                                    int* __restrict__ csr_src,
                                                    int N, int E) {
    __shared__ int deg[256];
    __shared__ int cur[256];
    __shared__ int tmp[256];
    int b = blockIdx.x, tid = threadIdx.x;
    int ebase = bucket_base[b], eend = bucket_base[b + 1];
    deg[tid] = 0;
    __syncthreads();
    for (int e = ebase + tid; e < eend; e += 256)
        atomicAdd(&deg[ebuf[e] >> 16], 1);
    __syncthreads();
    int v = deg[tid];
    tmp[tid] = v;
    __syncthreads();
    for (int off = 1; off < 256; off <<= 1) {
        int t = (tid >= off) ? tmp[tid - off] : 0;
        __syncthreads();
        tmp[tid] += t;
        __syncthreads();
    }
    int excl = tmp[tid] - v;
    int node = b * 256 + tid;
    if (node < N) row_ptr[node] = ebase + excl;
    if (b == 0 && tid == 0) row_ptr[N] = E;
    cur[tid] = excl;
    __syncthreads();
    for (int e = ebase + tid; e < eend; e += 256) {
        unsigned pk = ebuf[e];
        int r = atomicAdd(&cur[pk >> 16], 1);
        csr_src[ebase + r] = (int)(pk & 0xFFFFu);
    }
}

// ---------------------------------------------------------------------------
// Node transform, register-resident: no LDS, no barriers. Wave = one 16-row
// x 80-col tile. B-frags are direct 16B loads from the pre-transposed
// augmented Wt (20KB, L1-resident); A-frags direct 16B loads from x.
//   h = x@W_src (packed bf16), alpha_src = col 64, alpha_dst = col 65.
// ---------------------------------------------------------------------------
template <int K, bool INBF16>
__global__ __launch_bounds__(256) void nt_reg(
    const void* __restrict__ x_,              // [N][K] fp32 or bf16
    const unsigned short* __restrict__ Wt,    // [80][K] bf16 augmented
    unsigned* __restrict__ hb_out,            // [N][32] packed bf16x2
    float* __restrict__ alpha_src, float* __restrict__ alpha_dst, int N) {
    int tid = threadIdx.x;
    int wid = tid >> 6, l = tid & 63;
    int rowbase = (blockIdx.x * 4 + wid) * 16;
    if (rowbase >= N) return;
    int jcol = l & 15, kg = (l >> 4) * 8;

    int r = rowbase + jcol;
    if (r >= N) r = N - 1;                    // clamp; stores are guarded
    const float*          xr32 = (const float*)x_ + (size_t)r * K + kg;
    const unsigned short* xr16 = (const unsigned short*)x_ + (size_t)r * K + kg;

    f32x4 acc[5];
    #pragma unroll
    for (int t = 0; t < 5; ++t) acc[t] = (f32x4){0.f, 0.f, 0.f, 0.f};

    #pragma unroll
    for (int kt = 0; kt < K / 32; ++kt) {
        short8v a;
        if constexpr (INBF16) {
            a = *(const short8v*)(xr16 + kt * 32);
        } else {
            float4 xa = *(const float4*)(xr32 + kt * 32);
            float4 xb = *(const float4*)(xr32 + kt * 32 + 4);
            a[0] = (short)bf16bits(xa.x); a[1] = (short)bf16bits(xa.y);
            a[2] = (short)bf16bits(xa.z); a[3] = (short)bf16bits(xa.w);
            a[4] = (short)bf16bits(xb.x); a[5] = (short)bf16bits(xb.y);
            a[6] = (short)bf16bits(xb.z); a[7] = (short)bf16bits(xb.w);
        }
        int kbase = kt * 32 + kg;
        #pragma unroll
        for (int t = 0; t < 5; ++t) {
            short8v b = *(const short8v*)&Wt[(t * 16 + jcol) * K + kbase];
            acc[t] = __builtin_amdgcn_mfma_f32_16x16x32_bf16(a, b, acc[t], 0, 0, 0);
        }
    }

    // C layout: col = l&15 (tile t -> col t*16+jcol), row = (l>>4)*4 + reg
    int rbase = rowbase + (l >> 4) * 4;
    #pragma unroll
    for (int t = 0; t < 4; ++t) {
        #pragma unroll
        for (int rr = 0; rr < 4; ++rr) {
            float v = acc[t][rr];
            float w = __shfl_xor(v, 1);
            int row = rbase + rr;
            if (!(l & 1) && row < N)
                hb_out[(size_t)row * 32 + t * 8 + (jcol >> 1)] = pack2bf(v, w);
        }
    }
    #pragma unroll
    for (int rr = 0; rr < 4; ++rr) {
        int row = rbase + rr;
        if (row < N) {
            if (jcol == 0) alpha_src[row] = acc[4][rr];
            if (jcol == 1) alpha_dst[row] = acc[4][rr];
        }
    }
}

// ---------------------------------------------------------------------------
// Aggregation (R7 known-good): wave per dst node. Direct-exp softmax (logits
// O(10), fp32-exp safe; ratio identical to max-subtracted). Logit phase
// lane = edge; gather phase half-wave per edge, lane = u32 (2 bf16 feats);
// 16-edge groups = 8 loads in flight; lanes >= cnt carry p=0,s=0 (no guards).
// ---------------------------------------------------------------------------
template <bool OUTBF16>
__global__ __launch_bounds__(256) void aggregate(
    const int* __restrict__ row_ptr, const int* __restrict__ csr_src,
    const float* __restrict__ alpha_src, const float* __restrict__ alpha_dst,
    const unsigned* __restrict__ hb,    // [N][32] packed bf16x2
    const float* __restrict__ bias,     // [64]
    void* __restrict__ out_,            // fp32 [N][64] or packed bf16 [N][32]
    int N) {
    int wid = threadIdx.x >> 6, lane = threadIdx.x & 63;
    int node = blockIdx.x * 4 + wid;
    if (node >= N) return;

    int beg = row_ptr[node], end = row_ptr[node + 1];
    float adst = alpha_dst[node];
    int half = lane >> 5, sub = lane & 31;

    float dL = 0.f;
    float aA[4] = {0.f, 0.f, 0.f, 0.f};
    float aB[4] = {0.f, 0.f, 0.f, 0.f};

    for (int c = beg; c < end; c += 64) {
        int cnt = end - c;
        cnt = (cnt < 64) ? cnt : 64;

        int s = 0;
        float p = 0.f;
        if (lane < cnt) {
            s = csr_src[c + lane];
            float t = alpha_src[s] + adst;
            t = (t > 0.f) ? t : NEG_SLOPE * t;
            p = __expf(fminf(t, 60.f));
            dL += p;
        }

        for (int j = 0; j < cnt; j += 16) {
            int   sv[8];
            float pv[8];
            unsigned uv[8];
            #pragma unroll
            for (int i = 0; i < 8; ++i) {
                int e = j + 2 * i + half;
                sv[i] = __shfl(s, e);
                pv[i] = __shfl(p, e);
            }
            #pragma unroll
            for (int i = 0; i < 8; ++i)
                uv[i] = hb[(size_t)sv[i] * 32 + sub];
            #pragma unroll
            for (int i = 0; i < 8; ++i) {
                aA[i & 3] = fmaf(pv[i], blo(uv[i]), aA[i & 3]);
                aB[i & 3] = fmaf(pv[i], bhi(uv[i]), aB[i & 3]);
            }
        }
    }
    float denom = dL;
    #pragma unroll
    for (int off = 32; off; off >>= 1) denom += __shfl_xor(denom, off);

    float accA = (aA[0] + aA[1]) + (aA[2] + aA[3]);
    float accB = (aB[0] + aB[1]) + (aB[2] + aB[3]);
    accA += __shfl_xor(accA, 32);
    accB += __shfl_xor(accB, 32);
    int srcl = lane >> 1;
    float vA = __shfl(accA, srcl);
    float vB = __shfl(accB, srcl);
    float val = (lane & 1) ? vB : vA;
    float r = (denom > 0.f) ? (val / denom) : 0.f;
    float fv = tanhf(r + bias[lane]);

    if constexpr (OUTBF16) {
        float fw = __shfl_xor(fv, 1);
        if (!(lane & 1))
            ((unsigned*)out_)[(size_t)node * 32 + (lane >> 1)] = pack2bf(fv, fw);
    } else {
        ((float*)out_)[(size_t)node * 64 + lane] = fv;
    }
}

// ---------------------------------------------------------------------------
extern "C" void kernel_launch(void* const* d_in, const int* in_sizes, int n_in,
                              void* d_out, int out_size, void* d_ws, size_t ws_size,
                              hipStream_t stream) {
    const float* x      = (const float*)d_in[0];
    const int*   src    = (const int*)  d_in[1];
    const int*   dst    = (const int*)  d_in[2];
    const float* W1_src = (const float*)d_in[3];
    const float* W1_dst = (const float*)d_in[4];
    const float* a1_src = (const float*)d_in[5];
    const float* a1_dst = (const float*)d_in[6];
    const float* b1     = (const float*)d_in[7];
    const float* W2_src = (const float*)d_in[8];
    const float* W2_dst = (const float*)d_in[9];
    const float* a2_src = (const float*)d_in[10];
    const float* a2_dst = (const float*)d_in[11];
    const float* b2     = (const float*)d_in[12];
    float* out = (float*)d_out;

    const int N = in_sizes[0] / 128;
    const int E = in_sizes[1];
    const int NB = (N + 255) / 256;

    char* ws = (char*)d_ws;
    size_t off = 0;
    auto alloc = [&](size_t bytes) {
        void* p = ws + off;
        off += (bytes + 255) & ~(size_t)255;
        return p;
    };
    unsigned* hbuf1  = (unsigned*)alloc((size_t)N * 32 * 4);  // h layer-1 (bf16x2)
    unsigned* h1buf  = (unsigned*)alloc((size_t)N * 32 * 4);  // tanh'd agg1 (bf16x2)
    unsigned* hbuf2  = (unsigned*)alloc((size_t)N * 32 * 4);  // h layer-2 (bf16x2)
    float* alpha_s1  = (float*)alloc((size_t)N * 4);
    float* alpha_d1  = (float*)alloc((size_t)N * 4);
    float* alpha_s2  = (float*)alloc((size_t)N * 4);
    float* alpha_d2  = (float*)alloc((size_t)N * 4);
    int*   row_ptr   = (int*)  alloc((size_t)(N + 1) * 4);
    int*   csr_src   = (int*)  alloc((size_t)E * 4);
    int*   partials  = (int*)  alloc(NHB * 256 * 4);
    int*   bucket_base   = (int*)alloc(257 * 4);
    int*   bucket_cursor = (int*)alloc(256 * 4);
    unsigned short* Wt1 = (unsigned short*)alloc(80 * 128 * 2);
    unsigned short* Wt2 = (unsigned short*)alloc(80 * 64 * 2);
    unsigned* ebuf   = (unsigned*)alloc((size_t)E * 4);
    (void)ws_size;

    const int eb3  = (E + EPB - 1) / EPB;
    const int nwb  = (N + 3) / 4;            // wave-per-node kernels
    const int ntb  = (N + 63) / 64;          // nt_reg: 4 tiles of 16 rows / block

    // Prep: hist partials + both augmented weight transposes
    prep<<<NHB + 2, 256, 0, stream>>>(dst, partials, E,
                                      W1_src, a1_src, W1_dst, a1_dst,
                                      W2_src, a2_src, W2_dst, a2_dst, Wt1, Wt2);
    // CSR chain
    bucket_scan<<<1, 256, 0, stream>>>(partials, bucket_base, bucket_cursor);
    bucket_scatter<<<eb3, 256, 0, stream>>>(src, dst, bucket_cursor, ebuf, E);
    bucket_build<<<NB, 256, 0, stream>>>(ebuf, bucket_base, row_ptr, csr_src, N, E);

    // Layer 1
    nt_reg<128, false><<<ntb, 256, 0, stream>>>(x, Wt1, hbuf1, alpha_s1, alpha_d1, N);
    aggregate<true><<<nwb, 256, 0, stream>>>(row_ptr, csr_src, alpha_s1, alpha_d1,
                                             hbuf1, b1, h1buf, N);
    // Layer 2
    nt_reg<64, true><<<ntb, 256, 0, stream>>>(h1buf, Wt2, hbuf2, alpha_s2, alpha_d2, N);
    aggregate<false><<<nwb, 256, 0, stream>>>(row_ptr, csr_src, alpha_s2, alpha_d2,
                                              hbuf2, b2, out, N);
}